// Round 1
// baseline (2083.840 us; speedup 1.0000x reference)
//
#include <hip/hip_runtime.h>

#define NTHREADS 256

// Geometry (fixed by the reference)
#define NB   4
#define CIN  64
#define HH   256
#define WW   256
#define CH   128   // q/k/v channels (2*d)
#define NPOS 100   // 10x10 tile (8x8 patch + 1 halo)
#define XSTR 68    // padded row stride for xt [pos][c]
#define QSTR 68    // padded row stride for qp/kp/vp/corr [c][px]

// LDS layout (floats):
//  qp   @ 0      : 128*68 = 8704
//  kp   @ 8704   : 8704
//  vp   @ 17408  : 8704
//  xt   @ 26112  : 100*68 = 6800   [pos][c]
//  hid  @ 32912  : 64*100 = 6400   [o][pos]
//  corr @ 26112  : 128*68 = 8704 (aliases xt+hid, which are dead by then)
//  mu   @ 39312  : 64
//  rs   @ 39376  : 64
// total 39440 floats = 157,760 B  (<= 160 KiB)

__global__ __launch_bounds__(NTHREADS)
void fsas_fused(const float* __restrict__ x,
                const float* __restrict__ w1,    // [384][64]
                const float* __restrict__ wdw,   // [384][3][3]
                const float* __restrict__ wout,  // [64][128]
                const float* __restrict__ lnw,   // [128]
                const float* __restrict__ lnb,   // [128]
                float* __restrict__ out)         // [4][64][256][256]
{
    __shared__ float smem[39440];
    float* qp   = smem;
    float* kp   = smem + 8704;
    float* vp   = smem + 17408;
    float* xt   = smem + 26112;
    float* hid  = smem + 32912;
    float* corr = smem + 26112;  // alias
    float* mu   = smem + 39312;
    float* rs   = smem + 39376;

    const int tid = threadIdx.x;
    const int pw  = blockIdx.x;
    const int ph  = blockIdx.y;
    const int b   = blockIdx.z;
    const int h0  = ph * 8;
    const int w0  = pw * 8;

    // ---- 1) load x tile (10x10 incl. halo, zero padded) as xt[pos][c] ----
    for (int idx = tid; idx < NPOS * CIN; idx += NTHREADS) {
        int c = idx / NPOS, pos = idx - c * NPOS;
        int r = pos / 10, q = pos - r * 10;
        int h = h0 - 1 + r, w = w0 - 1 + q;
        float v = 0.f;
        if ((unsigned)h < (unsigned)HH && (unsigned)w < (unsigned)WW)
            v = x[((b * CIN + c) * HH + h) * WW + w];
        xt[pos * XSTR + c] = v;
    }
    __syncthreads();

    // ---- 2) hidden (1x1 conv) + depthwise 3x3, 6 chunks of 64 channels ----
    const float4* w1v = (const float4*)w1;  // [384][16] float4 rows
    for (int chunk = 0; chunk < 6; ++chunk) {
        // hidden[o][pos] for o in [chunk*64, chunk*64+64), pos in [0,100)
        // each task: 4 consecutive o at one pos (register blocked)
        for (int task = tid; task < 1600; task += NTHREADS) {
            int og = task / 100, pos = task - og * 100;
            int o0 = og * 4;
            const float4* wr = w1v + (chunk * 64 + o0) * 16;
            const float4* xr = (const float4*)(xt + pos * XSTR);
            float a0 = 0.f, a1 = 0.f, a2 = 0.f, a3 = 0.f;
#pragma unroll
            for (int c4 = 0; c4 < 16; ++c4) {
                float4 xv = xr[c4];
                float4 wa = wr[c4];
                float4 wb = wr[16 + c4];
                float4 wc = wr[32 + c4];
                float4 wd = wr[48 + c4];
                a0 += xv.x * wa.x + xv.y * wa.y + xv.z * wa.z + xv.w * wa.w;
                a1 += xv.x * wb.x + xv.y * wb.y + xv.z * wb.z + xv.w * wb.w;
                a2 += xv.x * wc.x + xv.y * wc.y + xv.z * wc.z + xv.w * wc.w;
                a3 += xv.x * wd.x + xv.y * wd.y + xv.z * wd.z + xv.w * wd.w;
            }
            hid[(o0 + 0) * NPOS + pos] = a0;
            hid[(o0 + 1) * NPOS + pos] = a1;
            hid[(o0 + 2) * NPOS + pos] = a2;
            hid[(o0 + 3) * NPOS + pos] = a3;
        }
        __syncthreads();

        // depthwise 3x3 (cross-correlation, SAME) -> q/k/v patch rows
        float* dstbuf = smem + (chunk >> 1) * 8704;   // qp/kp/vp
        int rowbase = (chunk & 1) * 64;
        const float* wd0 = wdw + chunk * 64 * 9;
        for (int idx = tid; idx < 4096; idx += NTHREADS) {
            int oc = idx >> 6, p = idx & 63;
            int py = p >> 3, px = p & 7;
            const float* wr = wd0 + oc * 9;
            const float* hr = hid + oc * NPOS + py * 10 + px;
            float s = wr[0] * hr[0]  + wr[1] * hr[1]  + wr[2] * hr[2]
                    + wr[3] * hr[10] + wr[4] * hr[11] + wr[5] * hr[12]
                    + wr[6] * hr[20] + wr[7] * hr[21] + wr[8] * hr[22];
            dstbuf[(rowbase + oc) * QSTR + p] = s;
        }
        __syncthreads();
    }

    // ---- 3) per-channel 8x8 circular convolution  corr = q (*) k ----
    // rows: 128 channels x 8 output rows; each thread computes full 8-wide rows
    for (int row = tid; row < 1024; row += NTHREADS) {
        int c = row >> 3, i = row & 7;
        const float* qr = qp + c * QSTR;
        const float* kr = kp + c * QSTR;
        float o_[8] = {0.f, 0.f, 0.f, 0.f, 0.f, 0.f, 0.f, 0.f};
#pragma unroll
        for (int a = 0; a < 8; ++a) {
            float4 qa = *(const float4*)(qr + a * 8);
            float4 qb = *(const float4*)(qr + a * 8 + 4);
            int kri = (i - a) & 7;
            float4 ka = *(const float4*)(kr + kri * 8);
            float4 kb = *(const float4*)(kr + kri * 8 + 4);
            float qv[8] = {qa.x, qa.y, qa.z, qa.w, qb.x, qb.y, qb.z, qb.w};
            float kv[8] = {ka.x, ka.y, ka.z, ka.w, kb.x, kb.y, kb.z, kb.w};
#pragma unroll
            for (int j = 0; j < 8; ++j) {
#pragma unroll
                for (int bb = 0; bb < 8; ++bb)
                    o_[j] += qv[bb] * kv[(j - bb) & 7];
            }
        }
        float* cr = corr + c * QSTR + i * 8;
#pragma unroll
        for (int j = 0; j < 8; ++j) cr[j] = o_[j];
    }
    __syncthreads();

    // ---- 4) LayerNorm stats over 128 channels per pixel ----
    if (tid < 64) {
        float s = 0.f, s2 = 0.f;
        for (int c = 0; c < CH; ++c) {
            float v = corr[c * QSTR + tid];
            s += v; s2 += v * v;
        }
        float m = s * (1.f / 128.f);
        float var = s2 * (1.f / 128.f) - m * m;
        mu[tid] = m;
        rs[tid] = rsqrtf(var + 1e-5f);
    }
    __syncthreads();

    // ---- 5) normalize, affine, gate by v (in place) ----
    for (int idx = tid; idx < CH * 64; idx += NTHREADS) {
        int c = idx >> 6, p = idx & 63;
        float v = corr[c * QSTR + p];
        v = (v - mu[p]) * rs[p] * lnw[c] + lnb[c];
        corr[c * QSTR + p] = v * vp[c * QSTR + p];
    }
    __syncthreads();

    // ---- 6) projection 128 -> 64 and store (4 o x 4 px per thread) ----
    {
        int og = tid & 15, pg = tid >> 4;
        int o0 = og * 4, p0 = pg * 4;
        float acc[16];
#pragma unroll
        for (int i = 0; i < 16; ++i) acc[i] = 0.f;
        for (int c = 0; c < CH; ++c) {
            float4 cv = *(const float4*)(corr + c * QSTR + p0);
            float wv0 = wout[(o0 + 0) * CH + c];
            float wv1 = wout[(o0 + 1) * CH + c];
            float wv2 = wout[(o0 + 2) * CH + c];
            float wv3 = wout[(o0 + 3) * CH + c];
            acc[0]  += wv0 * cv.x; acc[1]  += wv0 * cv.y; acc[2]  += wv0 * cv.z; acc[3]  += wv0 * cv.w;
            acc[4]  += wv1 * cv.x; acc[5]  += wv1 * cv.y; acc[6]  += wv1 * cv.z; acc[7]  += wv1 * cv.w;
            acc[8]  += wv2 * cv.x; acc[9]  += wv2 * cv.y; acc[10] += wv2 * cv.z; acc[11] += wv2 * cv.w;
            acc[12] += wv3 * cv.x; acc[13] += wv3 * cv.y; acc[14] += wv3 * cv.z; acc[15] += wv3 * cv.w;
        }
        int py = p0 >> 3, px = p0 & 7;
#pragma unroll
        for (int i = 0; i < 4; ++i) {
            float4 r;
            r.x = acc[i * 4 + 0]; r.y = acc[i * 4 + 1];
            r.z = acc[i * 4 + 2]; r.w = acc[i * 4 + 3];
            *(float4*)(out + (((size_t)(b * 64 + o0 + i) * HH) + h0 + py) * WW + w0 + px) = r;
        }
    }
}

extern "C" void kernel_launch(void* const* d_in, const int* in_sizes, int n_in,
                              void* d_out, int out_size, void* d_ws, size_t ws_size,
                              hipStream_t stream) {
    const float* x    = (const float*)d_in[0];
    const float* w1   = (const float*)d_in[1];
    const float* wdw  = (const float*)d_in[2];
    const float* wout = (const float*)d_in[3];
    const float* lnw  = (const float*)d_in[4];
    const float* lnb  = (const float*)d_in[5];
    float* o = (float*)d_out;

    dim3 grid(32, 32, NB);   // (pw, ph, b)
    dim3 block(NTHREADS);
    fsas_fused<<<grid, block, 0, stream>>>(x, w1, wdw, wout, lnw, lnb, o);
}

// Round 2
// 1011.893 us; speedup vs baseline: 2.0593x; 2.0593x over previous
//
#include <hip/hip_runtime.h>

#define NTHREADS 1024

// Geometry (fixed by the reference)
#define NB   4
#define CIN  64
#define HH   256
#define WW   256
#define CH   128   // q/k/v channels (2*d)
#define NPOS 100   // 10x10 tile (8x8 patch + 1 halo)
#define XSTR 68    // padded row stride for xt [pos][c]
#define QSTR 68    // padded row stride for qp/kp/vp/corr [c][px]

// LDS layout (floats):
//  qp   @ 0      : 128*68 = 8704   (dead after corr -> reused as `red`)
//  kp   @ 8704   : 8704
//  vp   @ 17408  : 8704
//  xt   @ 26112  : 100*68 = 6800   [pos][c]
//  hid  @ 32912  : 64*100 = 6400   [o][pos]
//  corr @ 26112  : 128*68 = 8704 (aliases xt+hid, dead by then)
//  mu   @ 39312  : 64
//  rs   @ 39376  : 64
// total 39440 floats = 157,760 B  (<= 160 KiB, 1 block/CU, 16 waves)

__global__ __launch_bounds__(NTHREADS)
void fsas_fused(const float* __restrict__ x,
                const float* __restrict__ w1,    // [384][64]
                const float* __restrict__ wdw,   // [384][3][3]
                const float* __restrict__ wout,  // [64][128]
                const float* __restrict__ lnw,   // [128]
                const float* __restrict__ lnb,   // [128]
                float* __restrict__ out)         // [4][64][256][256]
{
    __shared__ float smem[39440];
    float* qp   = smem;
    float* kp   = smem + 8704;
    float* vp   = smem + 17408;
    float* xt   = smem + 26112;
    float* hid  = smem + 32912;
    float* corr = smem + 26112;  // alias (xt+hid dead)
    float* red  = smem;          // alias (qp dead after corr)
    float* mu   = smem + 39312;
    float* rs   = smem + 39376;

    const int tid = threadIdx.x;
    const int pw  = blockIdx.x;
    const int ph  = blockIdx.y;
    const int b   = blockIdx.z;
    const int h0  = ph * 8;
    const int w0  = pw * 8;

    // ---- 1) load x tile (10x10 incl. halo, zero padded) as xt[pos][c] ----
    for (int idx = tid; idx < NPOS * CIN; idx += NTHREADS) {
        int c = idx / NPOS, pos = idx - c * NPOS;
        int r = pos / 10, q = pos - r * 10;
        int h = h0 - 1 + r, w = w0 - 1 + q;
        float v = 0.f;
        if ((unsigned)h < (unsigned)HH && (unsigned)w < (unsigned)WW)
            v = x[((b * CIN + c) * HH + h) * WW + w];
        xt[pos * XSTR + c] = v;
    }
    __syncthreads();

    // ---- 2) hidden (1x1 conv) + depthwise 3x3, 6 chunks of 64 channels ----
    // wave-uniform o-groups so weight loads go through the scalar path
    for (int chunk = 0; chunk < 6; ++chunk) {
        {
            int og  = __builtin_amdgcn_readfirstlane((int)(tid >> 7)); // 0..7 (2 waves each)
            int pos = tid & 127;
            if (pos < NPOS) {
                const float* wr = w1 + (chunk * 64 + og * 8) * 64;   // scalar base
                const float4* xr = (const float4*)(xt + pos * XSTR);
                float acc[8] = {0.f, 0.f, 0.f, 0.f, 0.f, 0.f, 0.f, 0.f};
#pragma unroll
                for (int c4 = 0; c4 < 16; ++c4) {
                    float4 xv = xr[c4];
#pragma unroll
                    for (int oo = 0; oo < 8; ++oo) {
                        const float* w = wr + oo * 64 + c4 * 4;      // uniform -> s_load
                        acc[oo] += xv.x * w[0] + xv.y * w[1] + xv.z * w[2] + xv.w * w[3];
                    }
                }
#pragma unroll
                for (int oo = 0; oo < 8; ++oo)
                    hid[(og * 8 + oo) * NPOS + pos] = acc[oo];
            }
        }
        __syncthreads();

        // depthwise 3x3 (cross-correlation, SAME) -> q/k/v patch rows
        {
            float* dstbuf = smem + (chunk >> 1) * 8704;   // qp/kp/vp
            int rowbase = (chunk & 1) * 64;
#pragma unroll
            for (int pass = 0; pass < 4; ++pass) {
                int oc = pass * 16 + __builtin_amdgcn_readfirstlane((int)(tid >> 6)); // wave-uniform
                int p  = tid & 63;
                int py = p >> 3, px = p & 7;
                const float* wr = wdw + (chunk * 64 + oc) * 9;       // uniform -> s_load
                const float* hr = hid + oc * NPOS + py * 10 + px;
                float s = wr[0] * hr[0]  + wr[1] * hr[1]  + wr[2] * hr[2]
                        + wr[3] * hr[10] + wr[4] * hr[11] + wr[5] * hr[12]
                        + wr[6] * hr[20] + wr[7] * hr[21] + wr[8] * hr[22];
                dstbuf[(rowbase + oc) * QSTR + p] = s;
            }
        }
        __syncthreads();
    }

    // ---- 3) per-channel 8x8 circular convolution  corr = q (*) k ----
    // 1024 rows (128 ch x 8 out-rows), exactly one per thread
    {
        int c = tid >> 3, i = tid & 7;
        const float* qr = qp + c * QSTR;
        const float* kr = kp + c * QSTR;
        float o_[8] = {0.f, 0.f, 0.f, 0.f, 0.f, 0.f, 0.f, 0.f};
#pragma unroll
        for (int a = 0; a < 8; ++a) {
            float4 qa = *(const float4*)(qr + a * 8);
            float4 qb = *(const float4*)(qr + a * 8 + 4);
            int kri = (i - a) & 7;
            float4 ka = *(const float4*)(kr + kri * 8);
            float4 kb = *(const float4*)(kr + kri * 8 + 4);
            float qv[8] = {qa.x, qa.y, qa.z, qa.w, qb.x, qb.y, qb.z, qb.w};
            float kv[8] = {ka.x, ka.y, ka.z, ka.w, kb.x, kb.y, kb.z, kb.w};
#pragma unroll
            for (int j = 0; j < 8; ++j) {
#pragma unroll
                for (int bb = 0; bb < 8; ++bb)
                    o_[j] += qv[bb] * kv[(j - bb) & 7];
            }
        }
        float tmp[8];
#pragma unroll
        for (int j = 0; j < 8; ++j) tmp[j] = o_[j];
        __syncthreads();   // qp/kp reads done before corr overwrite? corr aliases xt/hid only — safe; barrier orders vs stage 2 anyway
        float* cr = corr + c * QSTR + i * 8;
#pragma unroll
        for (int j = 0; j < 8; ++j) cr[j] = tmp[j];
    }
    __syncthreads();

    // ---- 4) LayerNorm stats: 16 partial groups x 64 px, tree combine ----
    {
        int px = tid & 63, grp = tid >> 6;   // grp 0..15
        float s = 0.f, s2 = 0.f;
#pragma unroll
        for (int i = 0; i < 8; ++i) {
            float v = corr[(i * 16 + grp) * QSTR + px];
            s += v; s2 += v * v;
        }
        red[grp * 64 + px] = s;
        red[1024 + grp * 64 + px] = s2;
    }
    __syncthreads();
    if (tid < 64) {
        float s = 0.f, s2 = 0.f;
#pragma unroll
        for (int g = 0; g < 16; ++g) {
            s  += red[g * 64 + tid];
            s2 += red[1024 + g * 64 + tid];
        }
        float m = s * (1.f / 128.f);
        float var = s2 * (1.f / 128.f) - m * m;
        mu[tid] = m;
        rs[tid] = rsqrtf(var + 1e-5f);
    }
    __syncthreads();

    // ---- 5) normalize, affine, gate by v (in place, float4) ----
    for (int idx = tid; idx < CH * 16; idx += NTHREADS) {
        int c = idx >> 4, p4 = (idx & 15) * 4;
        float4 v  = *(float4*)(corr + c * QSTR + p4);
        float4 g  = *(const float4*)(vp + c * QSTR + p4);
        float4 m  = *(const float4*)(mu + p4);
        float4 r  = *(const float4*)(rs + p4);
        float wc = lnw[c], bc = lnb[c];
        v.x = ((v.x - m.x) * r.x * wc + bc) * g.x;
        v.y = ((v.y - m.y) * r.y * wc + bc) * g.y;
        v.z = ((v.z - m.z) * r.z * wc + bc) * g.z;
        v.w = ((v.w - m.w) * r.w * wc + bc) * g.w;
        *(float4*)(corr + c * QSTR + p4) = v;
    }
    __syncthreads();

    // ---- 6) projection 128 -> 64 and store (1 o x 4 px per thread) ----
    {
        int o = tid >> 4, pg = tid & 15, p0 = pg * 4;
        const float* wr = wout + o * CH;
        float a0 = 0.f, a1 = 0.f, a2 = 0.f, a3 = 0.f;
#pragma unroll 8
        for (int c = 0; c < CH; ++c) {
            float4 cv = *(const float4*)(corr + c * QSTR + p0);
            float w = wr[c];
            a0 += w * cv.x; a1 += w * cv.y; a2 += w * cv.z; a3 += w * cv.w;
        }
        int py = p0 >> 3, px = p0 & 7;
        float4 r; r.x = a0; r.y = a1; r.z = a2; r.w = a3;
        *(float4*)(out + (((size_t)(b * 64 + o) * HH) + h0 + py) * WW + w0 + px) = r;
    }
}

extern "C" void kernel_launch(void* const* d_in, const int* in_sizes, int n_in,
                              void* d_out, int out_size, void* d_ws, size_t ws_size,
                              hipStream_t stream) {
    const float* x    = (const float*)d_in[0];
    const float* w1   = (const float*)d_in[1];
    const float* wdw  = (const float*)d_in[2];
    const float* wout = (const float*)d_in[3];
    const float* lnw  = (const float*)d_in[4];
    const float* lnb  = (const float*)d_in[5];
    float* o = (float*)d_out;

    dim3 grid(32, 32, NB);   // (pw, ph, b)
    dim3 block(NTHREADS);
    fsas_fused<<<grid, block, 0, stream>>>(x, w1, wdw, wout, lnw, lnb, o);
}

// Round 4
// 593.417 us; speedup vs baseline: 3.5116x; 1.7052x over previous
//
#include <hip/hip_runtime.h>

#define NTHREADS 1024

// Geometry (fixed by the reference)
#define NB   4
#define CIN  64
#define HH   256
#define WW   256
#define CH   128   // q/k/v channels (2*d)
#define QSTR 68    // padded row stride for qp/kp/vp/corr [c][px]

// LDS layout (float offsets):
//  qp    @ 0      : 128*68 = 8704   (reused as `red` after correlation)
//  kp    @ 8704   : 8704
//  vp    @ 17408  : 8704
//  xfrag @ 26112  : 8192 bf16 = 4096 floats  (B fragments, MFMA order)
//  hid   @ 30208  : 16384 bf16 = 8192 floats ([o 0..127][pos 0..127])
//  corr  @ 26112  : 8704 floats (aliases xfrag+hid, dead after chunks)
//  mu    @ 38400  : 64
//  rs    @ 38464  : 64
// total 38528 floats = 154,112 B  (<= 160 KiB, 1 block/CU, 16 waves)

typedef short s16x8 __attribute__((ext_vector_type(8)));
typedef float f32x16 __attribute__((ext_vector_type(16)));

__device__ inline unsigned short f2bf(float f) {      // RNE f32 -> bf16
    unsigned u = __builtin_bit_cast(unsigned, f);
    u += 0x7FFFu + ((u >> 16) & 1u);
    return (unsigned short)(u >> 16);
}
__device__ inline unsigned pk2bf(float a, float b) {  // packed (lo=a, hi=b)
    return (unsigned)f2bf(a) | ((unsigned)f2bf(b) << 16);
}

__global__ __launch_bounds__(NTHREADS)
void fsas_fused(const float* __restrict__ x,
                const float* __restrict__ w1,    // [384][64]
                const float* __restrict__ wdw,   // [384][3][3]
                const float* __restrict__ wout,  // [64][128]
                const float* __restrict__ lnw,   // [128]
                const float* __restrict__ lnb,   // [128]
                float* __restrict__ out)         // [4][64][256][256]
{
    __shared__ float smem[38528];
    float* qp   = smem;
    float* kp   = smem + 8704;
    float* vp   = smem + 17408;
    unsigned short* xfrag = (unsigned short*)(smem + 26112);
    unsigned short* hid   = (unsigned short*)(smem + 30208);
    float* corr = smem + 26112;  // alias (xfrag+hid dead by then)
    float* red  = smem;          // alias (qp dead after correlation)
    float* mu   = smem + 38400;
    float* rs   = smem + 38464;

    const int tid = threadIdx.x;
    const int wv  = tid >> 6;      // wave 0..15
    const int ln  = tid & 63;
    const int l32 = ln & 31, half = ln >> 5;
    const int pw  = blockIdx.x;
    const int ph  = blockIdx.y;
    const int b   = blockIdx.z;
    const int h0  = ph * 8;
    const int w0  = pw * 8;

    // ---- 0) zero xfrag (pos 100..127 padding must be 0) ----
    for (int i = tid; i < 4096; i += NTHREADS) ((float*)xfrag)[i] = 0.f;
    __syncthreads();

    // ---- 1) load x tile (10x10 incl. halo) into B-fragment order, bf16 ----
    // B frag for tile (nt, ks): lane l holds X[pos = nt*32 + (l&31)][c = ks*16 + (l>>5)*8 + b], b=0..7
    for (int idx = tid; idx < 6400; idx += NTHREADS) {
        int c = idx / 100, pos = idx - c * 100;
        int r = pos / 10, q = pos - r * 10;
        int h = h0 - 1 + r, w = w0 - 1 + q;
        float v = 0.f;
        if ((unsigned)h < (unsigned)HH && (unsigned)w < (unsigned)WW)
            v = x[((b * CIN + c) * HH + h) * WW + w];
        int lane = (pos & 31) + 32 * ((c >> 3) & 1);
        int nt = pos >> 5, ks = c >> 4, bb = c & 7;
        xfrag[((nt * 4 + ks) * 64 + lane) * 8 + bb] = f2bf(v);
    }
    __syncthreads();

    // ---- 2) hidden = w1 . x  (MFMA)  +  depthwise 3x3, 3 chunks of 128 ch ----
    const int mt = wv >> 2;    // m-tile 0..3 within chunk (32 o each)
    const int nt = wv & 3;     // n-tile 0..3 (32 pos each)
    for (int chunk = 0; chunk < 3; ++chunk) {
        // A fragments from global w1 (L2-hot): rows o = chunk*128+mt*32+l32
        const float* wbase = w1 + (chunk * 128 + mt * 32 + l32) * 64 + half * 8;
        s16x8 afr[4];
#pragma unroll
        for (int ks = 0; ks < 4; ++ks) {
            float4 f0 = *(const float4*)(wbase + ks * 16);
            float4 f1 = *(const float4*)(wbase + ks * 16 + 4);
            uint4 u;
            u.x = pk2bf(f0.x, f0.y); u.y = pk2bf(f0.z, f0.w);
            u.z = pk2bf(f1.x, f1.y); u.w = pk2bf(f1.z, f1.w);
            afr[ks] = __builtin_bit_cast(s16x8, u);
        }
        f32x16 acc = {};
#pragma unroll
        for (int ks = 0; ks < 4; ++ks) {
            s16x8 bfr = *(const s16x8*)(xfrag + ((nt * 4 + ks) * 64 + ln) * 8);
            acc = __builtin_amdgcn_mfma_f32_32x32x16_bf16(afr[ks], bfr, acc, 0, 0, 0);
        }
        // D -> hid (bf16): o = mt*32 + (r&3)+8*(r>>2)+4*half, pos = nt*32+l32
        {
            int pos = nt * 32 + l32;
#pragma unroll
            for (int r = 0; r < 16; ++r) {
                int o_l = mt * 32 + (r & 3) + 8 * (r >> 2) + 4 * half;
                hid[o_l * 128 + pos] = f2bf(acc[r]);
            }
        }
        __syncthreads();

        // depthwise 3x3 -> q/k/v: thread handles (oc = tid>>3, py = tid&7), 8 px
        {
            int oc = tid >> 3, py = tid & 7;
            const float* wr = wdw + (chunk * 128 + oc) * 9;
            float wgt[9];
#pragma unroll
            for (int t = 0; t < 9; ++t) wgt[t] = wr[t];
            const unsigned short* hrow = hid + oc * 128 + py * 10;
            float hv[3][10];
#pragma unroll
            for (int rr = 0; rr < 3; ++rr) {
#pragma unroll
                for (int cc = 0; cc < 5; ++cc) {
                    unsigned u = *(const unsigned*)(hrow + rr * 10 + cc * 2);
                    hv[rr][cc * 2]     = __builtin_bit_cast(float, u << 16);
                    hv[rr][cc * 2 + 1] = __builtin_bit_cast(float, u & 0xFFFF0000u);
                }
            }
            float* dst = (smem + chunk * 8704) + oc * QSTR + py * 8;
            float o_[8];
#pragma unroll
            for (int px = 0; px < 8; ++px) {
                o_[px] = wgt[0] * hv[0][px] + wgt[1] * hv[0][px + 1] + wgt[2] * hv[0][px + 2]
                       + wgt[3] * hv[1][px] + wgt[4] * hv[1][px + 1] + wgt[5] * hv[1][px + 2]
                       + wgt[6] * hv[2][px] + wgt[7] * hv[2][px + 1] + wgt[8] * hv[2][px + 2];
            }
            float4 r0; r0.x = o_[0]; r0.y = o_[1]; r0.z = o_[2]; r0.w = o_[3];
            float4 r1; r1.x = o_[4]; r1.y = o_[5]; r1.z = o_[6]; r1.w = o_[7];
            *(float4*)(dst)     = r0;
            *(float4*)(dst + 4) = r1;
        }
        __syncthreads();
    }

    // ---- 3) per-channel 8x8 circular convolution  corr = q (*) k ----
    {
        int c = tid >> 3, i = tid & 7;
        const float* qr = qp + c * QSTR;
        const float* kr = kp + c * QSTR;
        float o_[8] = {0.f, 0.f, 0.f, 0.f, 0.f, 0.f, 0.f, 0.f};
#pragma unroll
        for (int a = 0; a < 8; ++a) {
            float4 qa = *(const float4*)(qr + a * 8);
            float4 qb = *(const float4*)(qr + a * 8 + 4);
            int kri = (i - a) & 7;
            float4 ka = *(const float4*)(kr + kri * 8);
            float4 kb = *(const float4*)(kr + kri * 8 + 4);
            float qv[8] = {qa.x, qa.y, qa.z, qa.w, qb.x, qb.y, qb.z, qb.w};
            float kv[8] = {ka.x, ka.y, ka.z, ka.w, kb.x, kb.y, kb.z, kb.w};
#pragma unroll
            for (int j = 0; j < 8; ++j) {
#pragma unroll
                for (int bb = 0; bb < 8; ++bb)
                    o_[j] += qv[bb] * kv[(j - bb) & 7];
            }
        }
        float* cr = corr + c * QSTR + i * 8;
#pragma unroll
        for (int j = 0; j < 8; ++j) cr[j] = o_[j];
    }
    __syncthreads();

    // ---- 4) LayerNorm stats: 16 partial groups x 64 px, tree combine ----
    {
        int px = tid & 63, grp = tid >> 6;
        float s = 0.f, s2 = 0.f;
#pragma unroll
        for (int i = 0; i < 8; ++i) {
            float v = corr[(i * 16 + grp) * QSTR + px];
            s += v; s2 += v * v;
        }
        red[grp * 64 + px] = s;
        red[1024 + grp * 64 + px] = s2;
    }
    __syncthreads();
    if (tid < 64) {
        float s = 0.f, s2 = 0.f;
#pragma unroll
        for (int g = 0; g < 16; ++g) {
            s  += red[g * 64 + tid];
            s2 += red[1024 + g * 64 + tid];
        }
        float m = s * (1.f / 128.f);
        float var = s2 * (1.f / 128.f) - m * m;
        mu[tid] = m;
        rs[tid] = rsqrtf(var + 1e-5f);
    }
    __syncthreads();

    // ---- 5) normalize, affine, gate by v (in place, float4) ----
    for (int idx = tid; idx < CH * 16; idx += NTHREADS) {
        int c = idx >> 4, p4 = (idx & 15) * 4;
        float4 v  = *(float4*)(corr + c * QSTR + p4);
        float4 g  = *(const float4*)(vp + c * QSTR + p4);
        float4 m  = *(const float4*)(mu + p4);
        float4 r  = *(const float4*)(rs + p4);
        float wc = lnw[c], bc = lnb[c];
        v.x = ((v.x - m.x) * r.x * wc + bc) * g.x;
        v.y = ((v.y - m.y) * r.y * wc + bc) * g.y;
        v.z = ((v.z - m.z) * r.z * wc + bc) * g.z;
        v.w = ((v.w - m.w) * r.w * wc + bc) * g.w;
        *(float4*)(corr + c * QSTR + p4) = v;
    }
    __syncthreads();

    // ---- 6) projection 128 -> 64 and store (1 o x 4 px per thread) ----
    {
        int o = tid >> 4, pg = tid & 15, p0 = pg * 4;
        const float* wr = wout + o * CH;
        float a0 = 0.f, a1 = 0.f, a2 = 0.f, a3 = 0.f;
#pragma unroll 8
        for (int c = 0; c < CH; ++c) {
            float4 cv = *(const float4*)(corr + c * QSTR + p0);
            float w = wr[c];
            a0 += w * cv.x; a1 += w * cv.y; a2 += w * cv.z; a3 += w * cv.w;
        }
        int py = p0 >> 3, px = p0 & 7;
        float4 r; r.x = a0; r.y = a1; r.z = a2; r.w = a3;
        *(float4*)(out + (((size_t)(b * 64 + o) * HH) + h0 + py) * WW + w0 + px) = r;
    }
}

extern "C" void kernel_launch(void* const* d_in, const int* in_sizes, int n_in,
                              void* d_out, int out_size, void* d_ws, size_t ws_size,
                              hipStream_t stream) {
    const float* x    = (const float*)d_in[0];
    const float* w1   = (const float*)d_in[1];
    const float* wdw  = (const float*)d_in[2];
    const float* wout = (const float*)d_in[3];
    const float* lnw  = (const float*)d_in[4];
    const float* lnb  = (const float*)d_in[5];
    float* o = (float*)d_out;

    dim3 grid(32, 32, NB);   // (pw, ph, b)
    dim3 block(NTHREADS);
    fsas_fused<<<grid, block, 0, stream>>>(x, w1, wdw, wout, lnw, lnb, o);
}

// Round 5
// 546.228 us; speedup vs baseline: 3.8150x; 1.0864x over previous
//
#include <hip/hip_runtime.h>

#define NTHREADS 1024

// Geometry (fixed by the reference)
#define NB   4
#define CIN  64
#define HH   256
#define WW   256
#define CH   128   // q/k/v channels (2*d)
#define QSTR 68    // padded row stride for qp/kp/vp/corr [c][px]
#define HSTR 132   // padded u16 row stride for hid (breaks 8-way bank conflict)

// LDS layout (float offsets):
//  qp    @ 0      : 8704   [c][px] fp32 q   (dead after corr -> red, pbuf)
//  kp    @ 8704   : 8704   (dead after corr -> pbuf)
//  vp    @ 17408  : 8704   (dead after stage 5)
//  xfrag @ 26112  : 4096   (8192 bf16, B frags; dead after chunk MFMAs)
//  hid   @ 30208  : 8448   (128 x 132 u16; dead after chunk-2 dwconv)
//  corr  @ 26112  : 8704   fp32 (aliases xfrag + hid head, both dead)
//  bfrag @ 34816  : 4096   (8192 bf16 gated B-frags; aliases hid tail, dead)
//  red   @ 0      : 2048   (LN partials; qp dead)
//  pbuf  @ 0      : 17408  (proj partials 16r x 16seg x 68; qp+kp dead)
//  mu    @ 38912  : 64
//  rs    @ 38976  : 64
// total 39040 floats = 156,160 B  (<= 160 KiB, 1 block/CU, 16 waves)

typedef short s16x8 __attribute__((ext_vector_type(8)));
typedef float f32x16 __attribute__((ext_vector_type(16)));

__device__ inline unsigned short f2bf(float f) {      // RNE f32 -> bf16
    unsigned u = __builtin_bit_cast(unsigned, f);
    u += 0x7FFFu + ((u >> 16) & 1u);
    return (unsigned short)(u >> 16);
}
__device__ inline float bf2f(unsigned short s) {
    return __builtin_bit_cast(float, (unsigned)s << 16);
}
__device__ inline unsigned pk2bf(float a, float b) {  // packed (lo=a, hi=b)
    return (unsigned)f2bf(a) | ((unsigned)f2bf(b) << 16);
}

__global__ __launch_bounds__(NTHREADS)
void fsas_fused(const float* __restrict__ x,
                const float* __restrict__ w1,    // [384][64]
                const float* __restrict__ wdw,   // [384][3][3]
                const float* __restrict__ wout,  // [64][128]
                const float* __restrict__ lnw,   // [128]
                const float* __restrict__ lnb,   // [128]
                float* __restrict__ out)         // [4][64][256][256]
{
    __shared__ float smem[39040];
    float* qp   = smem;
    float* kp   = smem + 8704;
    float* vp   = smem + 17408;
    unsigned short* xfrag = (unsigned short*)(smem + 26112);
    unsigned short* hid   = (unsigned short*)(smem + 30208);
    float* corr = smem + 26112;  // alias
    unsigned short* bfrag = (unsigned short*)(smem + 34816);
    float* red  = smem;          // alias (qp)
    float* pbuf = smem;          // alias (qp+kp)
    float* mu   = smem + 38912;
    float* rs   = smem + 38976;

    const int tid = threadIdx.x;
    const int wv  = tid >> 6;      // wave 0..15
    const int ln  = tid & 63;
    const int l32 = ln & 31, half = ln >> 5;
    const int pw  = blockIdx.x;
    const int ph  = blockIdx.y;
    const int b   = blockIdx.z;
    const int h0  = ph * 8;
    const int w0  = pw * 8;

    // ---- 0) zero xfrag (pos 100..127 padding must be 0) ----
    for (int i = tid; i < 4096; i += NTHREADS) ((float*)xfrag)[i] = 0.f;
    __syncthreads();

    // ---- 1) load x tile (10x10 incl. halo) into B-fragment order, bf16 ----
    for (int idx = tid; idx < 6400; idx += NTHREADS) {
        int c = idx / 100, pos = idx - c * 100;
        int r = pos / 10, q = pos - r * 10;
        int h = h0 - 1 + r, w = w0 - 1 + q;
        float v = 0.f;
        if ((unsigned)h < (unsigned)HH && (unsigned)w < (unsigned)WW)
            v = x[((b * CIN + c) * HH + h) * WW + w];
        int lane = (pos & 31) + 32 * ((c >> 3) & 1);
        int nt = pos >> 5, ks = c >> 4, bb = c & 7;
        xfrag[((nt * 4 + ks) * 64 + lane) * 8 + bb] = f2bf(v);
    }
    __syncthreads();

    // ---- 2) hidden = w1 . x  (MFMA)  +  depthwise 3x3, 3 chunks of 128 ch ----
    const int mt = wv >> 2;    // m-tile 0..3 within chunk (32 o each)
    const int nt = wv & 3;     // n-tile 0..3 (32 pos each)
    for (int chunk = 0; chunk < 3; ++chunk) {
        const float* wbase = w1 + (chunk * 128 + mt * 32 + l32) * 64 + half * 8;
        s16x8 afr[4];
#pragma unroll
        for (int ks = 0; ks < 4; ++ks) {
            float4 f0 = *(const float4*)(wbase + ks * 16);
            float4 f1 = *(const float4*)(wbase + ks * 16 + 4);
            uint4 u;
            u.x = pk2bf(f0.x, f0.y); u.y = pk2bf(f0.z, f0.w);
            u.z = pk2bf(f1.x, f1.y); u.w = pk2bf(f1.z, f1.w);
            afr[ks] = __builtin_bit_cast(s16x8, u);
        }
        f32x16 acc = {};
#pragma unroll
        for (int ks = 0; ks < 4; ++ks) {
            s16x8 bfr = *(const s16x8*)(xfrag + ((nt * 4 + ks) * 64 + ln) * 8);
            acc = __builtin_amdgcn_mfma_f32_32x32x16_bf16(afr[ks], bfr, acc, 0, 0, 0);
        }
        {
            int pos = nt * 32 + l32;
#pragma unroll
            for (int r = 0; r < 16; ++r) {
                int o_l = mt * 32 + (r & 3) + 8 * (r >> 2) + 4 * half;
                hid[o_l * HSTR + pos] = f2bf(acc[r]);
            }
        }
        __syncthreads();

        // depthwise 3x3 -> q/k/v: thread handles (oc = tid>>3, py = tid&7), 8 px
        {
            int oc = tid >> 3, py = tid & 7;
            const float* wr = wdw + (chunk * 128 + oc) * 9;
            float wgt[9];
#pragma unroll
            for (int t = 0; t < 9; ++t) wgt[t] = wr[t];
            const unsigned short* hrow = hid + oc * HSTR + py * 10;
            float hv[3][10];
#pragma unroll
            for (int rr = 0; rr < 3; ++rr) {
#pragma unroll
                for (int cc = 0; cc < 5; ++cc) {
                    unsigned u = *(const unsigned*)(hrow + rr * 10 + cc * 2);
                    hv[rr][cc * 2]     = __builtin_bit_cast(float, u << 16);
                    hv[rr][cc * 2 + 1] = __builtin_bit_cast(float, u & 0xFFFF0000u);
                }
            }
            float* dst = (smem + chunk * 8704) + oc * QSTR + py * 8;
            float o_[8];
#pragma unroll
            for (int px = 0; px < 8; ++px) {
                o_[px] = wgt[0] * hv[0][px] + wgt[1] * hv[0][px + 1] + wgt[2] * hv[0][px + 2]
                       + wgt[3] * hv[1][px] + wgt[4] * hv[1][px + 1] + wgt[5] * hv[1][px + 2]
                       + wgt[6] * hv[2][px] + wgt[7] * hv[2][px + 1] + wgt[8] * hv[2][px + 2];
            }
            float4 r0; r0.x = o_[0]; r0.y = o_[1]; r0.z = o_[2]; r0.w = o_[3];
            float4 r1; r1.x = o_[4]; r1.y = o_[5]; r1.z = o_[6]; r1.w = o_[7];
            *(float4*)(dst)     = r0;
            *(float4*)(dst + 4) = r1;
        }
        __syncthreads();
    }

    // ---- 3) per-channel 8x8 circular convolution  corr = q (*) k ----
    {
        int c = tid >> 3, i = tid & 7;
        const float* qr = qp + c * QSTR;
        const float* kr = kp + c * QSTR;
        float o_[8] = {0.f, 0.f, 0.f, 0.f, 0.f, 0.f, 0.f, 0.f};
#pragma unroll
        for (int a = 0; a < 8; ++a) {
            float4 qa = *(const float4*)(qr + a * 8);
            float4 qb = *(const float4*)(qr + a * 8 + 4);
            int kri = (i - a) & 7;
            float4 ka = *(const float4*)(kr + kri * 8);
            float4 kb = *(const float4*)(kr + kri * 8 + 4);
            float qv[8] = {qa.x, qa.y, qa.z, qa.w, qb.x, qb.y, qb.z, qb.w};
            float kv[8] = {ka.x, ka.y, ka.z, ka.w, kb.x, kb.y, kb.z, kb.w};
#pragma unroll
            for (int j = 0; j < 8; ++j) {
#pragma unroll
                for (int bb = 0; bb < 8; ++bb)
                    o_[j] += qv[bb] * kv[(j - bb) & 7];
            }
        }
        float* cr = corr + c * QSTR + i * 8;
#pragma unroll
        for (int j = 0; j < 8; ++j) cr[j] = o_[j];
    }
    __syncthreads();

    // ---- 4) LayerNorm stats: 16 partial groups x 64 px, tree combine ----
    {
        int px = tid & 63, grp = tid >> 6;
        float s = 0.f, s2 = 0.f;
#pragma unroll
        for (int i = 0; i < 8; ++i) {
            float v = corr[(i * 16 + grp) * QSTR + px];
            s += v; s2 += v * v;
        }
        red[grp * 64 + px] = s;
        red[1024 + grp * 64 + px] = s2;
    }
    __syncthreads();
    if (tid < 64) {
        float s = 0.f, s2 = 0.f;
#pragma unroll
        for (int g = 0; g < 16; ++g) {
            s  += red[g * 64 + tid];
            s2 += red[1024 + g * 64 + tid];
        }
        float m = s * (1.f / 128.f);
        float var = s2 * (1.f / 128.f) - m * m;
        mu[tid] = m;
        rs[tid] = rsqrtf(var + 1e-5f);
    }
    __syncthreads();

    // ---- 5) normalize + affine + gate -> bf16 B-fragments for projection ----
    // wave wv: ntt = wv>>3 (px-tile), ks = wv&7 (k-step). lane: px = ntt*32+l32,
    // c = ks*16 + half*8 + b (b=0..7). One ds_write_b128 per lane.
    {
        int ntt = wv >> 3, ks = wv & 7;
        int px = ntt * 32 + l32;
        int cb = ks * 16 + half * 8;
        float m = mu[px], r = rs[px];
        unsigned pk[4];
#pragma unroll
        for (int g = 0; g < 4; ++g) {
            float v0 = corr[(cb + g * 2 + 0) * QSTR + px];
            float v1 = corr[(cb + g * 2 + 1) * QSTR + px];
            float g0 = vp[(cb + g * 2 + 0) * QSTR + px];
            float g1 = vp[(cb + g * 2 + 1) * QSTR + px];
            float w0c = lnw[cb + g * 2], w1c = lnw[cb + g * 2 + 1];
            float b0c = lnb[cb + g * 2], b1c = lnb[cb + g * 2 + 1];
            float t0 = ((v0 - m) * r * w0c + b0c) * g0;
            float t1 = ((v1 - m) * r * w1c + b1c) * g1;
            pk[g] = pk2bf(t0, t1);
        }
        uint4 u; u.x = pk[0]; u.y = pk[1]; u.z = pk[2]; u.w = pk[3];
        *(uint4*)(bfrag + ((ntt * 8 + ks) * 64 + ln) * 8) = u;
    }
    __syncthreads();

    // ---- 6) projection 128 -> 64 via MFMA (A = wout split hi+lo bf16) ----
    // wave wv: kseg = wv&3 (2 k-steps each), mtp = (wv>>2)&1, ntp = wv>>3
    {
        int kseg = wv & 3, mtp = (wv >> 2) & 1, ntp = wv >> 3;
        const float* wob = wout + (mtp * 32 + l32) * 128 + half * 8;
        f32x16 acc = {};
#pragma unroll
        for (int k2 = 0; k2 < 2; ++k2) {
            int ks = kseg * 2 + k2;
            float4 f0 = *(const float4*)(wob + ks * 16);
            float4 f1 = *(const float4*)(wob + ks * 16 + 4);
            float wf[8] = {f0.x, f0.y, f0.z, f0.w, f1.x, f1.y, f1.z, f1.w};
            unsigned short hi[8]; float lo[8];
#pragma unroll
            for (int t = 0; t < 8; ++t) {
                hi[t] = f2bf(wf[t]);
                lo[t] = wf[t] - bf2f(hi[t]);
            }
            uint4 uh, ul;
            uh.x = (unsigned)hi[0] | ((unsigned)hi[1] << 16);
            uh.y = (unsigned)hi[2] | ((unsigned)hi[3] << 16);
            uh.z = (unsigned)hi[4] | ((unsigned)hi[5] << 16);
            uh.w = (unsigned)hi[6] | ((unsigned)hi[7] << 16);
            ul.x = pk2bf(lo[0], lo[1]); ul.y = pk2bf(lo[2], lo[3]);
            ul.z = pk2bf(lo[4], lo[5]); ul.w = pk2bf(lo[6], lo[7]);
            s16x8 ah = __builtin_bit_cast(s16x8, uh);
            s16x8 al = __builtin_bit_cast(s16x8, ul);
            s16x8 bfr = *(const s16x8*)(bfrag + ((ntp * 8 + ks) * 64 + ln) * 8);
            acc = __builtin_amdgcn_mfma_f32_32x32x16_bf16(ah, bfr, acc, 0, 0, 0);
            acc = __builtin_amdgcn_mfma_f32_32x32x16_bf16(al, bfr, acc, 0, 0, 0);
        }
        // partials: pbuf[r][seg][ln]  (stride 68 per seg, 1088 per r)
        int seg = ntp * 8 + mtp * 4 + kseg;
#pragma unroll
        for (int r = 0; r < 16; ++r)
            pbuf[r * 1088 + seg * 68 + ln] = acc[r];
    }
    __syncthreads();

    // ---- 7) combine 4 k-partials and store ----
    {
        int o = tid >> 4, pg = tid & 15;
        int mtp = o >> 5, row = o & 31;
        int rg = row >> 3, rem = row & 7, hf = rem >> 2, ii = rem & 3;
        int r = rg * 4 + ii;
        int px0 = pg * 4;
        int ntp = px0 >> 5;
        int segb = ntp * 8 + mtp * 4;
        float v[4];
#pragma unroll
        for (int j = 0; j < 4; ++j) {
            int lane = ((px0 + j) & 31) + 32 * hf;
            const float* pb = pbuf + r * 1088 + segb * 68 + lane;
            v[j] = pb[0] + pb[68] + pb[136] + pb[204];
        }
        int py = px0 >> 3, wx = px0 & 7;
        float4 rr; rr.x = v[0]; rr.y = v[1]; rr.z = v[2]; rr.w = v[3];
        *(float4*)(out + (((size_t)(b * 64 + o) * HH) + h0 + py) * WW + w0 + wx) = rr;
    }
}

extern "C" void kernel_launch(void* const* d_in, const int* in_sizes, int n_in,
                              void* d_out, int out_size, void* d_ws, size_t ws_size,
                              hipStream_t stream) {
    const float* x    = (const float*)d_in[0];
    const float* w1   = (const float*)d_in[1];
    const float* wdw  = (const float*)d_in[2];
    const float* wout = (const float*)d_in[3];
    const float* lnw  = (const float*)d_in[4];
    const float* lnb  = (const float*)d_in[5];
    float* o = (float*)d_out;

    dim3 grid(32, 32, NB);   // (pw, ph, b)
    dim3 block(NTHREADS);
    fsas_fused<<<grid, block, 0, stream>>>(x, w1, wdw, wout, lnw, lnb, o);
}

// Round 6
// 379.419 us; speedup vs baseline: 5.4922x; 1.4396x over previous
//
#include <hip/hip_runtime.h>

#define NTHREADS 1024

// Geometry (fixed by the reference)
#define NB   4
#define CIN  64
#define HH   256
#define WW   256
#define CH   128

// LDS map (u16 units unless noted). Total 27,520 floats = 110,080 B.
//  q     u16 [0, 8192)        bf16, [c][slot^][8], slot = py ^ (c&7)
//  k     u16 [8192, 16384)
//  v     u16 [16384, 24576)
//  xfrag u16 [24576, 32768)   B-frags of x tile (dead after chunks)
//  hid   u16 [32768, 54272)   [ch][10 rows][16] stride 168 (dead after chunks)
//  corr  f32 @ float 12288, 8704 f  (aliases xfrag + hid head)
//  bfrag u16 [41984, 50176)   gated B-frags (aliases hid tail)
//  red   f32 @ 0, 2048 f      (aliases q — dead)
//  pbuf  f32 @ 0, 17408 f     (aliases q/k/v/xfrag/corr-head — all dead in stage 6)
//  lnw/lnb/mu/rs @ floats 27136/27264/27392/27456
#define Q_U16   0
#define K_U16   8192
#define V_U16   16384
#define XF_U16  24576
#define HID_U16 32768
#define HSTR16  168
#define CORR_F  12288
#define BF_U16  41984
#define LNW_F   27136
#define LNB_F   27264
#define MU_F    27392
#define RS_F    27456
#define SMEM_F  27520

typedef short s16x8 __attribute__((ext_vector_type(8)));
typedef float f32x16 __attribute__((ext_vector_type(16)));

__device__ inline unsigned short f2bf(float f) {      // RNE f32 -> bf16
    unsigned u = __builtin_bit_cast(unsigned, f);
    u += 0x7FFFu + ((u >> 16) & 1u);
    return (unsigned short)(u >> 16);
}
__device__ inline float bf2f(unsigned short s) {
    return __builtin_bit_cast(float, (unsigned)s << 16);
}
__device__ inline unsigned pk2bf(float a, float b) {  // packed (lo=a, hi=b)
    return (unsigned)f2bf(a) | ((unsigned)f2bf(b) << 16);
}

// ---- prepack: w1 + wout(hi/lo) -> bf16 MFMA A-fragment order in d_ws ----
// ws u16 layout: [0,24576) w1 frags; [24576,32768) wout-hi; [32768,40960) wout-lo
__global__ __launch_bounds__(256)
void fsas_prepack(const float* __restrict__ w1, const float* __restrict__ wout,
                  unsigned short* __restrict__ ws)
{
    int t = blockIdx.x * 256 + threadIdx.x;   // 0..40959
    if (t < 24576) {
        int b = t & 7, ln = (t >> 3) & 63, ks = (t >> 9) & 3, mtc = t >> 11;
        int l32 = ln & 31, half = ln >> 5;
        int o = mtc * 32 + l32;               // = chunk*128 + mt*32 + l32
        int kk = ks * 16 + half * 8 + b;
        ws[t] = f2bf(w1[o * 64 + kk]);
    } else if (t < 40960) {
        int idx = t - 24576;
        int lo = idx >= 8192;
        if (lo) idx -= 8192;
        int b = idx & 7, ln = (idx >> 3) & 63, ks = (idx >> 9) & 7, mtp = idx >> 12;
        int l32 = ln & 31, half = ln >> 5;
        int o = mtp * 32 + l32;
        int kk = ks * 16 + half * 8 + b;
        float v = wout[o * 128 + kk];
        unsigned short hi = f2bf(v);
        ws[t] = lo ? f2bf(v - bf2f(hi)) : hi;
    }
}

__global__ __launch_bounds__(NTHREADS, 4)
void fsas_fused(const float* __restrict__ x,
                const float* __restrict__ wdw,   // [384][3][3]
                const unsigned short* __restrict__ wsu,  // prepacked frags
                const float* __restrict__ lnw,
                const float* __restrict__ lnb,
                float* __restrict__ out)
{
    __shared__ float smem[SMEM_F];
    unsigned short* su = (unsigned short*)smem;
    float* corr = smem + CORR_F;
    float* red  = smem;
    float* pbuf = smem;
    float* lnwS = smem + LNW_F;
    float* lnbS = smem + LNB_F;
    float* muS  = smem + MU_F;
    float* rsS  = smem + RS_F;

    const int tid = threadIdx.x;
    const int wv  = tid >> 6;
    const int ln  = tid & 63;
    const int l32 = ln & 31, half = ln >> 5;
    const int pw  = blockIdx.x;
    const int ph  = blockIdx.y;
    const int b   = blockIdx.z;
    const int h0  = ph * 8;
    const int w0  = pw * 8;

    // ---- 0) zero xfrag pad + stage lnw/lnb ----
    for (int i = tid; i < 4096; i += NTHREADS) smem[CORR_F + i] = 0.f;  // xfrag region
    if (tid < 128) lnwS[tid] = lnw[tid];
    else if (tid < 256) lnbS[tid - 128] = lnb[tid - 128];
    __syncthreads();

    // ---- 1) x tile (10x10 + halo) -> bf16 B-fragments ----
    for (int idx = tid; idx < 6400; idx += NTHREADS) {
        int c = idx / 100, pos = idx - c * 100;
        int r = pos / 10, q = pos - r * 10;
        int h = h0 - 1 + r, w = w0 - 1 + q;
        float v = 0.f;
        if ((unsigned)h < (unsigned)HH && (unsigned)w < (unsigned)WW)
            v = x[((b * CIN + c) * HH + h) * WW + w];
        int lane = (pos & 31) + 32 * ((c >> 3) & 1);
        int nt = pos >> 5, ks = c >> 4, bb = c & 7;
        su[XF_U16 + ((nt * 4 + ks) * 64 + lane) * 8 + bb] = f2bf(v);
    }
    __syncthreads();

    // ---- 2) hidden = w1.x (MFMA) + depthwise 3x3, 3 chunks of 128 ch ----
    const int mt = wv >> 2, nt = wv & 3;
    const int pos = nt * 32 + l32;
    const int r10 = pos / 10, c10 = pos - r10 * 10;
    const int posoff = r10 * 16 + c10;
    const bool pvalid = pos < 100;
    const s16x8* waf = (const s16x8*)wsu;
    for (int chunk = 0; chunk < 3; ++chunk) {
        s16x8 afr[4];
#pragma unroll
        for (int ks = 0; ks < 4; ++ks)
            afr[ks] = waf[((chunk * 4 + mt) * 4 + ks) * 64 + ln];
        f32x16 acc = {};
#pragma unroll
        for (int ks = 0; ks < 4; ++ks) {
            s16x8 bfr = *(const s16x8*)(su + XF_U16 + ((nt * 4 + ks) * 64 + ln) * 8);
            acc = __builtin_amdgcn_mfma_f32_32x32x16_bf16(afr[ks], bfr, acc, 0, 0, 0);
        }
        if (pvalid) {
#pragma unroll
            for (int r = 0; r < 16; ++r) {
                int o_l = mt * 32 + (r & 3) + 8 * (r >> 2) + 4 * half;
                su[HID_U16 + o_l * HSTR16 + posoff] = f2bf(acc[r]);
            }
        }
        __syncthreads();

        // depthwise 3x3: thread = (oc, py); reads rows py..py+2 (16-aligned)
        {
            int oc = tid >> 3, py = tid & 7;
            const float* wr = wdw + (chunk * 128 + oc) * 9;
            float wgt[9];
#pragma unroll
            for (int t = 0; t < 9; ++t) wgt[t] = wr[t];
            const unsigned short* hb = su + HID_U16 + oc * HSTR16 + py * 16;
            float hv[3][12];
#pragma unroll
            for (int rr = 0; rr < 3; ++rr) {
                uint4 ua = *(const uint4*)(hb + rr * 16);
                uint2 ub = *(const uint2*)(hb + rr * 16 + 8);
                unsigned us[6] = {ua.x, ua.y, ua.z, ua.w, ub.x, ub.y};
#pragma unroll
                for (int t2 = 0; t2 < 6; ++t2) {
                    hv[rr][t2 * 2]     = __builtin_bit_cast(float, us[t2] << 16);
                    hv[rr][t2 * 2 + 1] = __builtin_bit_cast(float, us[t2] & 0xFFFF0000u);
                }
            }
            float o_[8];
#pragma unroll
            for (int px = 0; px < 8; ++px) {
                o_[px] = wgt[0] * hv[0][px] + wgt[1] * hv[0][px + 1] + wgt[2] * hv[0][px + 2]
                       + wgt[3] * hv[1][px] + wgt[4] * hv[1][px + 1] + wgt[5] * hv[1][px + 2]
                       + wgt[6] * hv[2][px] + wgt[7] * hv[2][px + 1] + wgt[8] * hv[2][px + 2];
            }
            unsigned short* dst = su + chunk * 8192 + oc * 64 + ((py ^ (oc & 7)) * 8);
            uint4 o4;
            o4.x = pk2bf(o_[0], o_[1]); o4.y = pk2bf(o_[2], o_[3]);
            o4.z = pk2bf(o_[4], o_[5]); o4.w = pk2bf(o_[6], o_[7]);
            *(uint4*)dst = o4;
        }
        __syncthreads();
    }

    // ---- 3) per-channel 8x8 circular convolution  corr = q (*) k ----
    {
        int c = tid >> 3, i = tid & 7, cs = c & 7;
        const unsigned short* qr = su + Q_U16 + c * 64;
        const unsigned short* kr = su + K_U16 + c * 64;
        float o_[8] = {0.f, 0.f, 0.f, 0.f, 0.f, 0.f, 0.f, 0.f};
#pragma unroll
        for (int a = 0; a < 8; ++a) {
            uint4 uq = *(const uint4*)(qr + (a ^ cs) * 8);
            int kri = (i - a) & 7;
            uint4 uk = *(const uint4*)(kr + (kri ^ cs) * 8);
            unsigned uqs[4] = {uq.x, uq.y, uq.z, uq.w};
            unsigned uks[4] = {uk.x, uk.y, uk.z, uk.w};
            float qv[8], kv[8];
#pragma unroll
            for (int t = 0; t < 4; ++t) {
                qv[t * 2]     = __builtin_bit_cast(float, uqs[t] << 16);
                qv[t * 2 + 1] = __builtin_bit_cast(float, uqs[t] & 0xFFFF0000u);
                kv[t * 2]     = __builtin_bit_cast(float, uks[t] << 16);
                kv[t * 2 + 1] = __builtin_bit_cast(float, uks[t] & 0xFFFF0000u);
            }
#pragma unroll
            for (int j = 0; j < 8; ++j) {
#pragma unroll
                for (int bb = 0; bb < 8; ++bb)
                    o_[j] += qv[bb] * kv[(j - bb) & 7];
            }
        }
        float* cr = corr + c * 68 + i * 8;
#pragma unroll
        for (int j = 0; j < 8; ++j) cr[j] = o_[j];
    }
    __syncthreads();

    // ---- 4) LayerNorm stats: 16 partial groups x 64 px ----
    {
        int px = tid & 63, grp = tid >> 6;
        float s = 0.f, s2 = 0.f;
#pragma unroll
        for (int i = 0; i < 8; ++i) {
            float v = corr[(i * 16 + grp) * 68 + px];
            s += v; s2 += v * v;
        }
        red[grp * 64 + px] = s;
        red[1024 + grp * 64 + px] = s2;
    }
    __syncthreads();
    if (tid < 64) {
        float s = 0.f, s2 = 0.f;
#pragma unroll
        for (int g = 0; g < 16; ++g) {
            s  += red[g * 64 + tid];
            s2 += red[1024 + g * 64 + tid];
        }
        float m = s * (1.f / 128.f);
        float var = s2 * (1.f / 128.f) - m * m;
        muS[tid] = m;
        rsS[tid] = rsqrtf(var + 1e-5f);
    }
    __syncthreads();

    // ---- 5) normalize + affine + gate(v) -> bf16 B-fragments ----
    {
        int ntt = wv >> 3, ks = wv & 7;
        int px = ntt * 32 + l32;
        int pslot = px >> 3, pcol = px & 7;
        float m = muS[px], rv = rsS[px];
        unsigned pk[4];
#pragma unroll
        for (int g = 0; g < 4; ++g) {
            int c0 = ks * 16 + half * 8 + g * 2;
            float v0 = corr[c0 * 68 + px];
            float v1 = corr[(c0 + 1) * 68 + px];
            float g0 = bf2f(su[V_U16 + c0 * 64 + ((pslot ^ (c0 & 7)) * 8) + pcol]);
            float g1 = bf2f(su[V_U16 + (c0 + 1) * 64 + ((pslot ^ ((c0 + 1) & 7)) * 8) + pcol]);
            float t0 = ((v0 - m) * rv * lnwS[c0] + lnbS[c0]) * g0;
            float t1 = ((v1 - m) * rv * lnwS[c0 + 1] + lnbS[c0 + 1]) * g1;
            pk[g] = pk2bf(t0, t1);
        }
        uint4 u; u.x = pk[0]; u.y = pk[1]; u.z = pk[2]; u.w = pk[3];
        *(uint4*)(su + BF_U16 + ((ntt * 8 + ks) * 64 + ln) * 8) = u;
    }
    __syncthreads();

    // ---- 6) projection 128 -> 64 via MFMA (prepacked wout hi+lo) ----
    {
        int kseg = wv & 3, mtp = (wv >> 2) & 1, ntp = wv >> 3;
        const s16x8* whi = (const s16x8*)(wsu + 24576);
        const s16x8* wlo = (const s16x8*)(wsu + 32768);
        f32x16 acc = {};
#pragma unroll
        for (int k2 = 0; k2 < 2; ++k2) {
            int ks = kseg * 2 + k2;
            s16x8 ah = whi[(mtp * 8 + ks) * 64 + ln];
            s16x8 al = wlo[(mtp * 8 + ks) * 64 + ln];
            s16x8 bfr = *(const s16x8*)(su + BF_U16 + ((ntp * 8 + ks) * 64 + ln) * 8);
            acc = __builtin_amdgcn_mfma_f32_32x32x16_bf16(ah, bfr, acc, 0, 0, 0);
            acc = __builtin_amdgcn_mfma_f32_32x32x16_bf16(al, bfr, acc, 0, 0, 0);
        }
        int seg = ntp * 8 + mtp * 4 + kseg;
#pragma unroll
        for (int r = 0; r < 16; ++r)
            pbuf[r * 1088 + seg * 68 + ln] = acc[r];
    }
    __syncthreads();

    // ---- 7) combine 4 k-partials (vectorized) and store ----
    {
        int o = tid >> 4, pg = tid & 15;
        int mtp = o >> 5, row = o & 31;
        int rg = row >> 3, rem = row & 7, hf = rem >> 2, ii = rem & 3;
        int r = rg * 4 + ii;
        int px0 = pg * 4;
        int ntp = px0 >> 5;
        int segb = ntp * 8 + mtp * 4;
        int lane0 = (px0 & 31) + 32 * hf;
        const float* pb = pbuf + r * 1088 + segb * 68 + lane0;
        float4 s0 = *(const float4*)(pb);
        float4 s1 = *(const float4*)(pb + 68);
        float4 s2 = *(const float4*)(pb + 136);
        float4 s3 = *(const float4*)(pb + 204);
        float4 rr;
        rr.x = s0.x + s1.x + s2.x + s3.x;
        rr.y = s0.y + s1.y + s2.y + s3.y;
        rr.z = s0.z + s1.z + s2.z + s3.z;
        rr.w = s0.w + s1.w + s2.w + s3.w;
        int py = px0 >> 3, wx = px0 & 7;
        *(float4*)(out + (((size_t)(b * 64 + o) * HH) + h0 + py) * WW + w0 + wx) = rr;
    }
}

extern "C" void kernel_launch(void* const* d_in, const int* in_sizes, int n_in,
                              void* d_out, int out_size, void* d_ws, size_t ws_size,
                              hipStream_t stream) {
    const float* x    = (const float*)d_in[0];
    const float* w1   = (const float*)d_in[1];
    const float* wdw  = (const float*)d_in[2];
    const float* wout = (const float*)d_in[3];
    const float* lnw  = (const float*)d_in[4];
    const float* lnb  = (const float*)d_in[5];
    float* o = (float*)d_out;
    unsigned short* ws = (unsigned short*)d_ws;

    fsas_prepack<<<160, 256, 0, stream>>>(w1, wout, ws);
    dim3 grid(32, 32, NB);
    fsas_fused<<<grid, dim3(NTHREADS), 0, stream>>>(x, wdw, ws, lnw, lnb, o);
}

// Round 7
// 357.524 us; speedup vs baseline: 5.8285x; 1.0612x over previous
//
#include <hip/hip_runtime.h>

#define NTHREADS 1024

// Geometry (fixed by the reference)
#define NB   4
#define HH   256
#define WW   256

// u16-unit LDS offsets. Total 40704 u16 = 81,408 B  -> 2 blocks/CU (162,816 <= 160 KiB... 2*81408=162816 <= 163840)
#define XF     0        // 8192 u16 bf16 x B-frags            (dead after stage 2)
#define HID    8192     // 7680 u16 f16 hid[64][10][12]       (dead after stage 2)
#define Q_U    15872    // 8192 u16 f16 [c][(slot^cs)*8+j]
#define K_U    24064    // 8192 u16 f16
#define V_U    32256    // 8192 u16 f16
#define CORRU  0        // 8192 u16 f16 (alias XF)
#define REDU   8192     // 4096 u16 = 2048 f32 (alias HID)
#define BFRU   24064    // 8192 u16 bf16 gated B-frags (alias K)
#define PBUFU  0        // 17408 u16 = 8704 f32 (alias CORR/RED/HID/Q-head)
#define MU_U   40448    // 128 u16 = 64 f32
#define RS_U   40576    // 128 u16 = 64 f32
#define SMEM_U 40704

typedef short s16x8 __attribute__((ext_vector_type(8)));
typedef float f32x16 __attribute__((ext_vector_type(16)));
typedef _Float16 h16x8 __attribute__((ext_vector_type(8)));
typedef _Float16 h16x4 __attribute__((ext_vector_type(4)));

__device__ inline unsigned short f2bf(float f) {      // RNE f32 -> bf16
    unsigned u = __builtin_bit_cast(unsigned, f);
    u += 0x7FFFu + ((u >> 16) & 1u);
    return (unsigned short)(u >> 16);
}
__device__ inline float bf2f(unsigned short s) {
    return __builtin_bit_cast(float, (unsigned)s << 16);
}
__device__ inline unsigned short f2h(float f) {
    _Float16 h = (_Float16)f;
    return __builtin_bit_cast(unsigned short, h);
}

// ---- prepack: w1 + wout(hi/lo) -> bf16 MFMA A-fragment order in d_ws ----
__global__ __launch_bounds__(256)
void fsas_prepack(const float* __restrict__ w1, const float* __restrict__ wout,
                  unsigned short* __restrict__ ws)
{
    int t = blockIdx.x * 256 + threadIdx.x;   // 0..40959
    if (t < 24576) {
        int b = t & 7, ln = (t >> 3) & 63, ks = (t >> 9) & 3, mtc = t >> 11;
        int l32 = ln & 31, half = ln >> 5;
        int o = mtc * 32 + l32;
        int kk = ks * 16 + half * 8 + b;
        ws[t] = f2bf(w1[o * 64 + kk]);
    } else if (t < 40960) {
        int idx = t - 24576;
        int lo = idx >= 8192;
        if (lo) idx -= 8192;
        int b = idx & 7, ln = (idx >> 3) & 63, ks = (idx >> 9) & 7, mtp = idx >> 12;
        int l32 = ln & 31, half = ln >> 5;
        int o = mtp * 32 + l32;
        int kk = ks * 16 + half * 8 + b;
        float v = wout[o * 128 + kk];
        unsigned short hi = f2bf(v);
        ws[t] = lo ? f2bf(v - bf2f(hi)) : hi;
    }
}

__global__ __launch_bounds__(NTHREADS, 8)
void fsas_fused(const float* __restrict__ x,
                const float* __restrict__ wdw,   // [384][3][3]
                const unsigned short* __restrict__ wsu,
                const float* __restrict__ lnw,
                const float* __restrict__ lnb,
                float* __restrict__ out)
{
    __shared__ unsigned short su[SMEM_U];

    const int tid = threadIdx.x;
    const int wv  = tid >> 6;
    const int ln  = tid & 63;
    const int l32 = ln & 31, half = ln >> 5;
    const int pw  = blockIdx.x;
    const int ph  = blockIdx.y;
    const int b   = blockIdx.z;
    const int h0  = ph * 8;
    const int w0  = pw * 8;

    // ---- 0) zero xfrag (pad pos 100..127 must be 0) ----
    {
        float* xfF = (float*)(su + XF);
        for (int i = tid; i < 4096; i += NTHREADS) xfF[i] = 0.f;
    }
    __syncthreads();

    // ---- 1) x tile (10x10 + halo) -> bf16 B-fragments ----
    for (int idx = tid; idx < 6400; idx += NTHREADS) {
        int c = idx / 100, pos = idx - c * 100;
        int r = pos / 10, q = pos - r * 10;
        int h = h0 - 1 + r, w = w0 - 1 + q;
        float v = 0.f;
        if ((unsigned)h < (unsigned)HH && (unsigned)w < (unsigned)WW)
            v = x[((b * 64 + c) * HH + h) * WW + w];
        int lane = (pos & 31) + 32 * ((c >> 3) & 1);
        int nt = pos >> 5, ks = c >> 4, bb = c & 7;
        su[XF + ((nt * 4 + ks) * 64 + lane) * 8 + bb] = f2bf(v);
    }
    __syncthreads();

    // ---- 2) six half-rounds: MFMA (64 out-ch) + depthwise 3x3 ----
    const s16x8* waf = (const s16x8*)wsu;
    const int mt2 = wv & 1, nt = (wv >> 1) & 3;       // for wv<8
    const int pos = nt * 32 + l32;
    const int r10 = pos / 10, c10 = pos - r10 * 10;
    const int posoff = r10 * 12 + c10;
    const bool pvalid = pos < 100;
    for (int rnd = 0; rnd < 6; ++rnd) {
        if (wv < 8) {
            int mtc = rnd * 2 + mt2;
            f32x16 acc = {};
#pragma unroll
            for (int ks = 0; ks < 4; ++ks) {
                s16x8 afr = waf[(mtc * 4 + ks) * 64 + ln];
                s16x8 bfr = *(const s16x8*)(su + XF + ((nt * 4 + ks) * 64 + ln) * 8);
                acc = __builtin_amdgcn_mfma_f32_32x32x16_bf16(afr, bfr, acc, 0, 0, 0);
            }
            if (pvalid) {
#pragma unroll
                for (int rr = 0; rr < 16; ++rr) {
                    int o_l = mt2 * 32 + (rr & 3) + 8 * (rr >> 2) + 4 * half;
                    su[HID + o_l * 120 + posoff] = f2h(acc[rr]);
                }
            }
        }
        __syncthreads();

        if (tid < 512) {
            int oc = tid >> 3, py = tid & 7;          // oc 0..63 local
            const float* wr = wdw + (rnd * 64 + oc) * 9;
            float wgt[9];
#pragma unroll
            for (int t = 0; t < 9; ++t) wgt[t] = wr[t];
            const unsigned short* hb = su + HID + oc * 120 + py * 12;
            _Float16 hh[3][12];
#pragma unroll
            for (int rr = 0; rr < 3; ++rr) {
                uint2 ua = *(const uint2*)(hb + rr * 12);
                uint2 ub = *(const uint2*)(hb + rr * 12 + 4);
                uint2 uc = *(const uint2*)(hb + rr * 12 + 8);
                h16x4 a = __builtin_bit_cast(h16x4, ua);
                h16x4 bq = __builtin_bit_cast(h16x4, ub);
                h16x4 cq = __builtin_bit_cast(h16x4, uc);
#pragma unroll
                for (int t = 0; t < 4; ++t) { hh[rr][t] = a[t]; hh[rr][4 + t] = bq[t]; hh[rr][8 + t] = cq[t]; }
            }
            float o_[8];
#pragma unroll
            for (int px = 0; px < 8; ++px) {
                o_[px] = wgt[0] * (float)hh[0][px] + wgt[1] * (float)hh[0][px + 1] + wgt[2] * (float)hh[0][px + 2]
                       + wgt[3] * (float)hh[1][px] + wgt[4] * (float)hh[1][px + 1] + wgt[5] * (float)hh[1][px + 2]
                       + wgt[6] * (float)hh[2][px] + wgt[7] * (float)hh[2][px + 1] + wgt[8] * (float)hh[2][px + 2];
            }
            int buf = rnd >> 1;                        // 0=q 1=k 2=v
            int cb  = (rnd & 1) * 64 + oc;             // channel in buffer
            int cs  = cb & 7;
            unsigned short* dst = su + Q_U + buf * 8192 + cb * 64 + ((py ^ cs) * 8);
            uint4 o4;
            o4.x = (unsigned)f2h(o_[0]) | ((unsigned)f2h(o_[1]) << 16);
            o4.y = (unsigned)f2h(o_[2]) | ((unsigned)f2h(o_[3]) << 16);
            o4.z = (unsigned)f2h(o_[4]) | ((unsigned)f2h(o_[5]) << 16);
            o4.w = (unsigned)f2h(o_[6]) | ((unsigned)f2h(o_[7]) << 16);
            *(uint4*)dst = o4;
        }
        __syncthreads();
    }

    // ---- 3) per-channel 8x8 circular convolution  corr = q (*) k (fp16 in, fp32 acc) ----
    {
        int c = tid >> 3, i = tid & 7, cs = c & 7;
        const unsigned short* qr = su + Q_U + c * 64;
        const unsigned short* kr = su + K_U + c * 64;
        float o_[8] = {0.f, 0.f, 0.f, 0.f, 0.f, 0.f, 0.f, 0.f};
#pragma unroll
        for (int a = 0; a < 8; ++a) {
            uint4 uq = *(const uint4*)(qr + ((a ^ cs) * 8));
            int kri = (i - a) & 7;
            uint4 uk = *(const uint4*)(kr + ((kri ^ cs) * 8));
            h16x8 qh = __builtin_bit_cast(h16x8, uq);
            h16x8 kh = __builtin_bit_cast(h16x8, uk);
            float qv[8], kv[8];
#pragma unroll
            for (int t = 0; t < 8; ++t) { qv[t] = (float)qh[t]; kv[t] = (float)kh[t]; }
#pragma unroll
            for (int j = 0; j < 8; ++j) {
#pragma unroll
                for (int bb = 0; bb < 8; ++bb)
                    o_[j] += qv[bb] * kv[(j - bb) & 7];
            }
        }
        uint4 o4;
        o4.x = (unsigned)f2h(o_[0]) | ((unsigned)f2h(o_[1]) << 16);
        o4.y = (unsigned)f2h(o_[2]) | ((unsigned)f2h(o_[3]) << 16);
        o4.z = (unsigned)f2h(o_[4]) | ((unsigned)f2h(o_[5]) << 16);
        o4.w = (unsigned)f2h(o_[6]) | ((unsigned)f2h(o_[7]) << 16);
        *(uint4*)(su + CORRU + c * 64 + ((i ^ cs) * 8)) = o4;
    }
    __syncthreads();

    // ---- 4) LayerNorm stats over 128 channels per pixel ----
    {
        float* redF = (float*)(su + REDU);
        int px = tid & 63, grp = tid >> 6;
        int prow = px >> 3, pcol = px & 7;
        float s = 0.f, s2 = 0.f;
#pragma unroll
        for (int i = 0; i < 8; ++i) {
            int c = i * 16 + grp;
            float v = (float)__builtin_bit_cast(_Float16,
                        su[CORRU + c * 64 + ((prow ^ (c & 7)) * 8) + pcol]);
            s += v; s2 += v * v;
        }
        redF[grp * 64 + px] = s;
        redF[1024 + grp * 64 + px] = s2;
    }
    __syncthreads();
    if (tid < 64) {
        float* redF = (float*)(su + REDU);
        float s = 0.f, s2 = 0.f;
#pragma unroll
        for (int g = 0; g < 16; ++g) {
            s  += redF[g * 64 + tid];
            s2 += redF[1024 + g * 64 + tid];
        }
        float m = s * (1.f / 128.f);
        float var = s2 * (1.f / 128.f) - m * m;
        ((float*)(su + MU_U))[tid] = m;
        ((float*)(su + RS_U))[tid] = rsqrtf(var + 1e-5f);
    }
    __syncthreads();

    // ---- 5) normalize + affine + gate(v) -> bf16 B-fragments (row per thread) ----
    {
        int c = tid >> 3, py = tid & 7, cs = c & 7;
        uint4 cu = *(const uint4*)(su + CORRU + c * 64 + ((py ^ cs) * 8));
        uint4 vu = *(const uint4*)(su + V_U   + c * 64 + ((py ^ cs) * 8));
        h16x8 ch = __builtin_bit_cast(h16x8, cu);
        h16x8 vh = __builtin_bit_cast(h16x8, vu);
        const float* muF = (const float*)(su + MU_U);
        const float* rsF = (const float*)(su + RS_U);
        float4 m0 = *(const float4*)(muF + py * 8);
        float4 m1 = *(const float4*)(muF + py * 8 + 4);
        float4 r0 = *(const float4*)(rsF + py * 8);
        float4 r1 = *(const float4*)(rsF + py * 8 + 4);
        float mm[8] = {m0.x, m0.y, m0.z, m0.w, m1.x, m1.y, m1.z, m1.w};
        float rr[8] = {r0.x, r0.y, r0.z, r0.w, r1.x, r1.y, r1.z, r1.w};
        float wc = lnw[c], bc = lnb[c];
        // bfrag address pieces: px = py*8+j
        int base = BFRU + (((py >> 2) * 8 + (c >> 4)) * 64 + 8 * (py & 3) + 32 * ((c >> 3) & 1)) * 8 + (c & 7);
#pragma unroll
        for (int j = 0; j < 8; ++j) {
            float t = (((float)ch[j] - mm[j]) * rr[j] * wc + bc) * (float)vh[j];
            su[base + j * 8] = f2bf(t);
        }
    }
    __syncthreads();

    // ---- 6) projection 128 -> 64 via MFMA (8 waves, 4-deep K, hi+lo wout) ----
    if (wv < 8) {
        int kseg = wv & 1, mtp = (wv >> 1) & 1, ntp = wv >> 2;  // ntp 0..1
        const s16x8* whi = (const s16x8*)(wsu + 24576);
        const s16x8* wlo = (const s16x8*)(wsu + 32768);
        f32x16 acc = {};
#pragma unroll
        for (int k2 = 0; k2 < 4; ++k2) {
            int ks = kseg * 4 + k2;
            s16x8 ah = whi[(mtp * 8 + ks) * 64 + ln];
            s16x8 al = wlo[(mtp * 8 + ks) * 64 + ln];
            s16x8 bfr = *(const s16x8*)(su + BFRU + ((ntp * 8 + ks) * 64 + ln) * 8);
            acc = __builtin_amdgcn_mfma_f32_32x32x16_bf16(ah, bfr, acc, 0, 0, 0);
            acc = __builtin_amdgcn_mfma_f32_32x32x16_bf16(al, bfr, acc, 0, 0, 0);
        }
        float* pbufF = (float*)(su + PBUFU);
        int seg = (ntp * 2 + mtp) * 2 + kseg;
#pragma unroll
        for (int r = 0; r < 16; ++r)
            pbufF[r * 544 + seg * 68 + ln] = acc[r];
    }
    __syncthreads();

    // ---- 7) combine 2 k-partials and store ----
    {
        const float* pbufF = (const float*)(su + PBUFU);
        int o = tid >> 4, pg = tid & 15;
        int mtp = o >> 5, row = o & 31;
        int rg = row >> 3, rem = row & 7, hf = rem >> 2, ii = rem & 3;
        int r = rg * 4 + ii;
        int px0 = pg * 4;
        int ntp = px0 >> 5;
        int lane0 = (px0 & 31) + 32 * hf;
        const float* pb = pbufF + r * 544 + ((ntp * 2 + mtp) * 2) * 68 + lane0;
        float4 s0 = *(const float4*)(pb);
        float4 s1 = *(const float4*)(pb + 68);
        float4 rr;
        rr.x = s0.x + s1.x; rr.y = s0.y + s1.y;
        rr.z = s0.z + s1.z; rr.w = s0.w + s1.w;
        int py = px0 >> 3, wx = px0 & 7;
        *(float4*)(out + (((size_t)(b * 64 + o) * HH) + h0 + py) * WW + w0 + wx) = rr;
    }
}

extern "C" void kernel_launch(void* const* d_in, const int* in_sizes, int n_in,
                              void* d_out, int out_size, void* d_ws, size_t ws_size,
                              hipStream_t stream) {
    const float* x    = (const float*)d_in[0];
    const float* w1   = (const float*)d_in[1];
    const float* wdw  = (const float*)d_in[2];
    const float* wout = (const float*)d_in[3];
    const float* lnw  = (const float*)d_in[4];
    const float* lnb  = (const float*)d_in[5];
    float* o = (float*)d_out;
    unsigned short* ws = (unsigned short*)d_ws;

    fsas_prepack<<<160, 256, 0, stream>>>(w1, wout, ws);
    dim3 grid(32, 32, NB);
    fsas_fused<<<grid, dim3(NTHREADS), 0, stream>>>(x, wdw, ws, lnw, lnb, o);
}

// Round 8
// 339.207 us; speedup vs baseline: 6.1433x; 1.0540x over previous
//
#include <hip/hip_runtime.h>

#define NTHREADS 512

// Geometry (fixed by the reference)
#define NB   4
#define HH   256
#define WW   256

// u16-unit LDS offsets. Total 40704 u16 = 81,408 B -> 2 blocks/CU (162,816 <= 163,840)
#define XF     0        // 8192 u16 bf16 x B-frags            (dead after stage 2)
#define HID    8192     // 7680 u16 f16 hid[64][10][12]       (dead after stage 2)
#define Q_U    15872    // 8192 u16 f16 [c][(slot^cs)*8+j]    (dead after stage 3)
#define K_U    24064    // 8192 u16 f16                       (dead after stage 3 -> BFRU)
#define V_U    32256    // 8192 u16 f16                       (dead after stage 5)
#define CORRU  0        // 8192 u16 f16 (alias XF)
#define REDU   8192     // 2048 u16 region for f32 partials (alias HID)
#define BFRU   24064    // 8192 u16 bf16 gated B-frags (alias K)
#define PBUFU  0        // 17408 u16 = 8704 f32 (alias XF/HID/Q-head — all dead in stage 6)
#define MU_U   40448    // 128 u16 = 64 f32
#define RS_U   40576    // 128 u16 = 64 f32
#define SMEM_U 40704

typedef short s16x8 __attribute__((ext_vector_type(8)));
typedef float f32x16 __attribute__((ext_vector_type(16)));
typedef _Float16 h16x8 __attribute__((ext_vector_type(8)));
typedef _Float16 h16x4 __attribute__((ext_vector_type(4)));

__device__ inline unsigned short f2bf(float f) {      // RNE f32 -> bf16
    unsigned u = __builtin_bit_cast(unsigned, f);
    u += 0x7FFFu + ((u >> 16) & 1u);
    return (unsigned short)(u >> 16);
}
__device__ inline float bf2f(unsigned short s) {
    return __builtin_bit_cast(float, (unsigned)s << 16);
}
__device__ inline unsigned short f2h(float f) {
    _Float16 h = (_Float16)f;
    return __builtin_bit_cast(unsigned short, h);
}

// ---- prepack: w1 + wout(hi/lo) -> bf16 MFMA A-fragment order in d_ws ----
__global__ __launch_bounds__(256)
void fsas_prepack(const float* __restrict__ w1, const float* __restrict__ wout,
                  unsigned short* __restrict__ ws)
{
    int t = blockIdx.x * 256 + threadIdx.x;   // 0..40959
    if (t < 24576) {
        int b = t & 7, ln = (t >> 3) & 63, ks = (t >> 9) & 3, mtc = t >> 11;
        int l32 = ln & 31, half = ln >> 5;
        int o = mtc * 32 + l32;
        int kk = ks * 16 + half * 8 + b;
        ws[t] = f2bf(w1[o * 64 + kk]);
    } else if (t < 40960) {
        int idx = t - 24576;
        int lo = idx >= 8192;
        if (lo) idx -= 8192;
        int b = idx & 7, ln = (idx >> 3) & 63, ks = (idx >> 9) & 7, mtp = idx >> 12;
        int l32 = ln & 31, half = ln >> 5;
        int o = mtp * 32 + l32;
        int kk = ks * 16 + half * 8 + b;
        float v = wout[o * 128 + kk];
        unsigned short hi = f2bf(v);
        ws[t] = lo ? f2bf(v - bf2f(hi)) : hi;
    }
}

__global__ __launch_bounds__(NTHREADS, 4)
void fsas_fused(const float* __restrict__ x,
                const float* __restrict__ wdw,   // [384][3][3]
                const unsigned short* __restrict__ wsu,
                const float* __restrict__ lnw,
                const float* __restrict__ lnb,
                float* __restrict__ out)
{
    __shared__ unsigned short su[SMEM_U];

    const int tid = threadIdx.x;
    const int wv  = tid >> 6;      // 0..7
    const int ln  = tid & 63;
    const int l32 = ln & 31, half = ln >> 5;
    const int pw  = blockIdx.x;
    const int ph  = blockIdx.y;
    const int b   = blockIdx.z;
    const int h0  = ph * 8;
    const int w0  = pw * 8;

    // ---- 0) zero xfrag (pad pos 100..127 must be 0) ----
    {
        float* xfF = (float*)(su + XF);
        for (int i = tid; i < 4096; i += NTHREADS) xfF[i] = 0.f;
    }
    __syncthreads();

    // ---- 1) x tile (10x10 + halo) -> bf16 B-fragments ----
    for (int idx = tid; idx < 6400; idx += NTHREADS) {
        int c = idx / 100, pos = idx - c * 100;
        int r = pos / 10, q = pos - r * 10;
        int h = h0 - 1 + r, w = w0 - 1 + q;
        float v = 0.f;
        if ((unsigned)h < (unsigned)HH && (unsigned)w < (unsigned)WW)
            v = x[((b * 64 + c) * HH + h) * WW + w];
        int lane = (pos & 31) + 32 * ((c >> 3) & 1);
        int nt = pos >> 5, ks = c >> 4, bb = c & 7;
        su[XF + ((nt * 4 + ks) * 64 + lane) * 8 + bb] = f2bf(v);
    }
    __syncthreads();

    // ---- 2) six half-rounds: MFMA (64 out-ch) + depthwise 3x3 ----
    const s16x8* waf = (const s16x8*)wsu;
    const int mt2 = wv & 1, nt = (wv >> 1) & 3;
    const int pos = nt * 32 + l32;
    const int r10 = pos / 10, c10 = pos - r10 * 10;
    const int posoff = r10 * 12 + c10;
    const bool pvalid = pos < 100;
    for (int rnd = 0; rnd < 6; ++rnd) {
        {
            int mtc = rnd * 2 + mt2;
            f32x16 acc = {};
#pragma unroll
            for (int ks = 0; ks < 4; ++ks) {
                s16x8 afr = waf[(mtc * 4 + ks) * 64 + ln];
                s16x8 bfr = *(const s16x8*)(su + XF + ((nt * 4 + ks) * 64 + ln) * 8);
                acc = __builtin_amdgcn_mfma_f32_32x32x16_bf16(afr, bfr, acc, 0, 0, 0);
            }
            if (pvalid) {
#pragma unroll
                for (int rr = 0; rr < 16; ++rr) {
                    int o_l = mt2 * 32 + (rr & 3) + 8 * (rr >> 2) + 4 * half;
                    su[HID + o_l * 120 + posoff] = f2h(acc[rr]);
                }
            }
        }
        __syncthreads();

        {
            int oc = tid >> 3, py = tid & 7;          // oc 0..63 local
            const float* wr = wdw + (rnd * 64 + oc) * 9;
            float wgt[9];
#pragma unroll
            for (int t = 0; t < 9; ++t) wgt[t] = wr[t];
            const unsigned short* hb = su + HID + oc * 120 + py * 12;
            _Float16 hh[3][12];
#pragma unroll
            for (int rr = 0; rr < 3; ++rr) {
                uint2 ua = *(const uint2*)(hb + rr * 12);
                uint2 ub = *(const uint2*)(hb + rr * 12 + 4);
                uint2 uc = *(const uint2*)(hb + rr * 12 + 8);
                h16x4 a = __builtin_bit_cast(h16x4, ua);
                h16x4 bq = __builtin_bit_cast(h16x4, ub);
                h16x4 cq = __builtin_bit_cast(h16x4, uc);
#pragma unroll
                for (int t = 0; t < 4; ++t) { hh[rr][t] = a[t]; hh[rr][4 + t] = bq[t]; hh[rr][8 + t] = cq[t]; }
            }
            float o_[8];
#pragma unroll
            for (int px = 0; px < 8; ++px) {
                o_[px] = wgt[0] * (float)hh[0][px] + wgt[1] * (float)hh[0][px + 1] + wgt[2] * (float)hh[0][px + 2]
                       + wgt[3] * (float)hh[1][px] + wgt[4] * (float)hh[1][px + 1] + wgt[5] * (float)hh[1][px + 2]
                       + wgt[6] * (float)hh[2][px] + wgt[7] * (float)hh[2][px + 1] + wgt[8] * (float)hh[2][px + 2];
            }
            int buf = rnd >> 1;                        // 0=q 1=k 2=v
            int cb  = (rnd & 1) * 64 + oc;
            int cs  = cb & 7;
            unsigned short* dst = su + Q_U + buf * 8192 + cb * 64 + ((py ^ cs) * 8);
            uint4 o4;
            o4.x = (unsigned)f2h(o_[0]) | ((unsigned)f2h(o_[1]) << 16);
            o4.y = (unsigned)f2h(o_[2]) | ((unsigned)f2h(o_[3]) << 16);
            o4.z = (unsigned)f2h(o_[4]) | ((unsigned)f2h(o_[5]) << 16);
            o4.w = (unsigned)f2h(o_[6]) | ((unsigned)f2h(o_[7]) << 16);
            *(uint4*)dst = o4;
        }
        __syncthreads();
    }

    // ---- 3) 8x8 circular conv, 2 output rows per thread (shared q loads) ----
    {
        int c = tid >> 2, i0 = tid & 3, cs = c & 7;
        const unsigned short* qr = su + Q_U + c * 64;
        const unsigned short* kr = su + K_U + c * 64;
        float o0[8] = {0.f,0.f,0.f,0.f,0.f,0.f,0.f,0.f};
        float o1[8] = {0.f,0.f,0.f,0.f,0.f,0.f,0.f,0.f};
#pragma unroll
        for (int a = 0; a < 8; ++a) {
            uint4 uq = *(const uint4*)(qr + ((a ^ cs) * 8));
            int k0 = (i0 - a) & 7, k1 = (i0 + 4 - a) & 7;
            uint4 uk0 = *(const uint4*)(kr + ((k0 ^ cs) * 8));
            uint4 uk1 = *(const uint4*)(kr + ((k1 ^ cs) * 8));
            h16x8 qh  = __builtin_bit_cast(h16x8, uq);
            h16x8 kh0 = __builtin_bit_cast(h16x8, uk0);
            h16x8 kh1 = __builtin_bit_cast(h16x8, uk1);
            float qv[8], kv0[8], kv1[8];
#pragma unroll
            for (int t = 0; t < 8; ++t) {
                qv[t] = (float)qh[t]; kv0[t] = (float)kh0[t]; kv1[t] = (float)kh1[t];
            }
#pragma unroll
            for (int j = 0; j < 8; ++j) {
#pragma unroll
                for (int bb = 0; bb < 8; ++bb) {
                    o0[j] += qv[bb] * kv0[(j - bb) & 7];
                    o1[j] += qv[bb] * kv1[(j - bb) & 7];
                }
            }
        }
        uint4 a4, b4;
        a4.x = (unsigned)f2h(o0[0]) | ((unsigned)f2h(o0[1]) << 16);
        a4.y = (unsigned)f2h(o0[2]) | ((unsigned)f2h(o0[3]) << 16);
        a4.z = (unsigned)f2h(o0[4]) | ((unsigned)f2h(o0[5]) << 16);
        a4.w = (unsigned)f2h(o0[6]) | ((unsigned)f2h(o0[7]) << 16);
        b4.x = (unsigned)f2h(o1[0]) | ((unsigned)f2h(o1[1]) << 16);
        b4.y = (unsigned)f2h(o1[2]) | ((unsigned)f2h(o1[3]) << 16);
        b4.z = (unsigned)f2h(o1[4]) | ((unsigned)f2h(o1[5]) << 16);
        b4.w = (unsigned)f2h(o1[6]) | ((unsigned)f2h(o1[7]) << 16);
        *(uint4*)(su + CORRU + c * 64 + ((i0 ^ cs) * 8)) = a4;
        *(uint4*)(su + CORRU + c * 64 + (((i0 + 4) ^ cs) * 8)) = b4;
    }
    __syncthreads();

    // ---- 4) LayerNorm stats: 8 partial groups x 64 px ----
    {
        float* redF = (float*)(su + REDU);
        int px = tid & 63, grp = tid >> 6;     // grp 0..7
        int prow = px >> 3, pcol = px & 7;
        float s = 0.f, s2 = 0.f;
#pragma unroll
        for (int i = 0; i < 16; ++i) {
            int c = i * 8 + grp;
            float v = (float)__builtin_bit_cast(_Float16,
                        su[CORRU + c * 64 + ((prow ^ (c & 7)) * 8) + pcol]);
            s += v; s2 += v * v;
        }
        redF[grp * 64 + px] = s;
        redF[512 + grp * 64 + px] = s2;
    }
    __syncthreads();
    if (tid < 64) {
        float* redF = (float*)(su + REDU);
        float s = 0.f, s2 = 0.f;
#pragma unroll
        for (int g = 0; g < 8; ++g) {
            s  += redF[g * 64 + tid];
            s2 += redF[512 + g * 64 + tid];
        }
        float m = s * (1.f / 128.f);
        float var = s2 * (1.f / 128.f) - m * m;
        ((float*)(su + MU_U))[tid] = m;
        ((float*)(su + RS_U))[tid] = rsqrtf(var + 1e-5f);
    }
    __syncthreads();

    // ---- 5) normalize + affine + gate(v) -> bf16 B-fragments (2 ch per thread) ----
    {
        int py = tid & 7, c0 = (tid >> 3) * 2;
        const float* muF = (const float*)(su + MU_U);
        const float* rsF = (const float*)(su + RS_U);
        float4 m0 = *(const float4*)(muF + py * 8);
        float4 m1 = *(const float4*)(muF + py * 8 + 4);
        float4 r0 = *(const float4*)(rsF + py * 8);
        float4 r1 = *(const float4*)(rsF + py * 8 + 4);
        float mm[8] = {m0.x, m0.y, m0.z, m0.w, m1.x, m1.y, m1.z, m1.w};
        float rr[8] = {r0.x, r0.y, r0.z, r0.w, r1.x, r1.y, r1.z, r1.w};
#pragma unroll
        for (int cc = 0; cc < 2; ++cc) {
            int c = c0 + cc, cs = c & 7;
            uint4 cu = *(const uint4*)(su + CORRU + c * 64 + ((py ^ cs) * 8));
            uint4 vu = *(const uint4*)(su + V_U   + c * 64 + ((py ^ cs) * 8));
            h16x8 ch = __builtin_bit_cast(h16x8, cu);
            h16x8 vh = __builtin_bit_cast(h16x8, vu);
            float wc = lnw[c], bc = lnb[c];
            int base = BFRU + (((py >> 2) * 8 + (c >> 4)) * 64 + 8 * (py & 3) + 32 * ((c >> 3) & 1)) * 8 + (c & 7);
#pragma unroll
            for (int j = 0; j < 8; ++j) {
                float t = (((float)ch[j] - mm[j]) * rr[j] * wc + bc) * (float)vh[j];
                su[base + j * 8] = f2bf(t);
            }
        }
    }
    __syncthreads();

    // ---- 6) projection 128 -> 64 via MFMA (8 waves, 4-deep K, hi+lo wout) ----
    {
        int kseg = wv & 1, mtp = (wv >> 1) & 1, ntp = wv >> 2;  // ntp 0..1
        const s16x8* whi = (const s16x8*)(wsu + 24576);
        const s16x8* wlo = (const s16x8*)(wsu + 32768);
        f32x16 acc = {};
#pragma unroll
        for (int k2 = 0; k2 < 4; ++k2) {
            int ks = kseg * 4 + k2;
            s16x8 ah = whi[(mtp * 8 + ks) * 64 + ln];
            s16x8 al = wlo[(mtp * 8 + ks) * 64 + ln];
            s16x8 bfr = *(const s16x8*)(su + BFRU + ((ntp * 8 + ks) * 64 + ln) * 8);
            acc = __builtin_amdgcn_mfma_f32_32x32x16_bf16(ah, bfr, acc, 0, 0, 0);
            acc = __builtin_amdgcn_mfma_f32_32x32x16_bf16(al, bfr, acc, 0, 0, 0);
        }
        float* pbufF = (float*)(su + PBUFU);
        int seg = (ntp * 2 + mtp) * 2 + kseg;
#pragma unroll
        for (int r = 0; r < 16; ++r)
            pbufF[r * 544 + seg * 68 + ln] = acc[r];
    }
    __syncthreads();

    // ---- 7) combine 2 k-partials and store (2 units per thread) ----
    {
        const float* pbufF = (const float*)(su + PBUFU);
#pragma unroll
        for (int it = 0; it < 2; ++it) {
            int u = tid + it * NTHREADS;     // 0..1023
            int o = u >> 4, pg = u & 15;
            int mtp = o >> 5, row = o & 31;
            int rg = row >> 3, rem = row & 7, hf = rem >> 2, ii = rem & 3;
            int r = rg * 4 + ii;
            int px0 = pg * 4;
            int ntp = px0 >> 5;
            int lane0 = (px0 & 31) + 32 * hf;
            const float* pb = pbufF + r * 544 + ((ntp * 2 + mtp) * 2) * 68 + lane0;
            float4 s0 = *(const float4*)(pb);
            float4 s1 = *(const float4*)(pb + 68);
            float4 rr;
            rr.x = s0.x + s1.x; rr.y = s0.y + s1.y;
            rr.z = s0.z + s1.z; rr.w = s0.w + s1.w;
            int py = px0 >> 3, wx = px0 & 7;
            *(float4*)(out + (((size_t)(b * 64 + o) * HH) + h0 + py) * WW + w0 + wx) = rr;
        }
    }
}

extern "C" void kernel_launch(void* const* d_in, const int* in_sizes, int n_in,
                              void* d_out, int out_size, void* d_ws, size_t ws_size,
                              hipStream_t stream) {
    const float* x    = (const float*)d_in[0];
    const float* w1   = (const float*)d_in[1];
    const float* wdw  = (const float*)d_in[2];
    const float* wout = (const float*)d_in[3];
    const float* lnw  = (const float*)d_in[4];
    const float* lnb  = (const float*)d_in[5];
    float* o = (float*)d_out;
    unsigned short* ws = (unsigned short*)d_ws;

    fsas_prepack<<<160, 256, 0, stream>>>(w1, wout, ws);
    dim3 grid(32, 32, NB);
    fsas_fused<<<grid, dim3(NTHREADS), 0, stream>>>(x, wdw, ws, lnw, lnb, o);
}